// Round 1
// baseline (1632.070 us; speedup 1.0000x reference)
//
#include <hip/hip_runtime.h>
#include <hip/hip_bf16.h>
#include <stdint.h>

// Problem constants
#define BATCH 2
#define CIN 128
#define COUT 512
#define DD 8
#define HH 32
#define WW2 32
#define PSPAT 8192          // D*H*W
#define NA 9                // anchors per position
#define NANCH 73728         // PSPAT*NA
#define PRE 2048
#define POST 300
#define NMS_TH 0.7f

// ws layout (byte offsets, all 16B aligned)
constexpr size_t OFF_WT  = 0;          // 27*128*512 f32   = 7,077,888 B
constexpr size_t OFF_WHT = 7077888;    // 512*80 f32       = 163,840 B
constexpr size_t OFF_X   = 7241728;    // 2*512*8192 f32   = 33,554,432 B
constexpr size_t OFF_SC  = 40796160;   // 2*73728 f32      = 589,824 B
constexpr size_t OFF_BX  = 41385984;   // 2*73728*6 f32    = 3,538,944 B
constexpr size_t OFF_SK  = 44924928;   // 2*2048 u64       = 32,768 B
constexpr size_t OFF_SB  = 44957696;   // 2*2048*6 f32     = 98,304 B
constexpr size_t OFF_MK  = 45056000;   // 2*2048*32 u64    = 1,048,576 B
constexpr size_t OFF_KB  = 46104576;   // 2 u64
constexpr size_t OFF_CNT = 46104592;   // 2 u32 (+pad)

// ---------------- weight transforms ----------------
__global__ void k_wtrans(const float* __restrict__ Wc, float* __restrict__ Wt) {
    int e = blockIdx.x * blockDim.x + threadIdx.x;
    if (e >= 27 * 128 * 512) return;
    int co  = e & 511;
    int ci  = (e >> 9) & 127;
    int tap = e >> 16;
    Wt[e] = Wc[(co * 128 + ci) * 27 + tap];
}

// Wht[c][q], q = og*20 + k (k<18 real), output o = og*18 + k
__global__ void k_whtrans(const float* __restrict__ Wcls, const float* __restrict__ Wbb,
                          float* __restrict__ Wht) {
    int e = blockIdx.x * blockDim.x + threadIdx.x;
    if (e >= 512 * 80) return;
    int q = e % 80;
    int c = e / 80;
    int og = q / 20, k = q % 20;
    int o = og * 18 + k;
    float v = 0.f;
    if (k < 18) v = (o < 18) ? Wcls[o * 512 + c] : Wbb[(o - 18) * 512 + c];
    Wht[e] = v;
}

// ---------------- conv3d 3x3x3 + bias + relu (implicit GEMM, fp32) ----------------
__global__ __launch_bounds__(256) void k_conv(const float* __restrict__ in,
                                              const float* __restrict__ Wt,
                                              const float* __restrict__ bconv,
                                              float* __restrict__ x) {
    __shared__ __align__(16) float As[32 * 64];
    __shared__ __align__(16) float Bs[32 * 64];
    const int tid = threadIdx.x;
    const int p0  = blockIdx.x * 64;   // spatial tile (fixed d, two h rows)
    const int co0 = blockIdx.y * 64;
    const int b   = blockIdx.z;
    const int d0  = p0 >> 10;
    const int h0  = (p0 >> 5) & 31;
    const int tco = (tid >> 4) * 4;
    const int tp  = (tid & 15) * 4;

    float acc[4][4] = {};

    for (int tap = 0; tap < 27; ++tap) {
        const int kd = tap / 9, kh = (tap / 3) % 3, kw = tap % 3;
        const int id = d0 + kd - 1;
        if (id < 0 || id >= DD) continue;   // uniform over block
        for (int cc = 0; cc < CIN; cc += 32) {
            __syncthreads();
            // stage A: input tile [kk 0..31][pp 0..63]
            #pragma unroll
            for (int i = 0; i < 8; ++i) {
                int e = tid + i * 256;
                int kk = e >> 6, pp = e & 63;
                int h = h0 + (pp >> 5);
                int w = pp & 31;
                int ih = h + kh - 1, iw = w + kw - 1;
                float v = 0.f;
                if ((unsigned)ih < 32u && (unsigned)iw < 32u)
                    v = in[(((b * CIN + cc + kk) * DD + id) << 10) + (ih << 5) + iw];
                As[kk * 64 + pp] = v;
            }
            // stage B: weights [kk][col]
            #pragma unroll
            for (int i = 0; i < 8; ++i) {
                int e = tid + i * 256;
                int kk = e >> 6, col = e & 63;
                Bs[kk * 64 + col] = Wt[(tap * 128 + cc + kk) * 512 + co0 + col];
            }
            __syncthreads();
            #pragma unroll
            for (int kk = 0; kk < 32; ++kk) {
                float4 a4 = *(const float4*)&As[kk * 64 + tp];
                float4 b4 = *(const float4*)&Bs[kk * 64 + tco];
                acc[0][0] += b4.x * a4.x; acc[0][1] += b4.x * a4.y; acc[0][2] += b4.x * a4.z; acc[0][3] += b4.x * a4.w;
                acc[1][0] += b4.y * a4.x; acc[1][1] += b4.y * a4.y; acc[1][2] += b4.y * a4.z; acc[1][3] += b4.y * a4.w;
                acc[2][0] += b4.z * a4.x; acc[2][1] += b4.z * a4.y; acc[2][2] += b4.z * a4.z; acc[2][3] += b4.z * a4.w;
                acc[3][0] += b4.w * a4.x; acc[3][1] += b4.w * a4.y; acc[3][2] += b4.w * a4.z; acc[3][3] += b4.w * a4.w;
            }
        }
    }
    #pragma unroll
    for (int i = 0; i < 4; ++i) {
        float bias = bconv[co0 + tco + i];
        float4 r;
        r.x = fmaxf(acc[i][0] + bias, 0.f);
        r.y = fmaxf(acc[i][1] + bias, 0.f);
        r.z = fmaxf(acc[i][2] + bias, 0.f);
        r.w = fmaxf(acc[i][3] + bias, 0.f);
        *(float4*)&x[((size_t)(b * COUT + co0 + tco + i) << 13) + p0 + tp] = r;
    }
}

// ---------------- heads GEMM + score/box epilogue ----------------
__global__ __launch_bounds__(256) void k_heads(const float* __restrict__ x,
                                               const float* __restrict__ Wht,
                                               const float* __restrict__ bcls,
                                               const float* __restrict__ bbb,
                                               const float* __restrict__ iminfo,
                                               float* __restrict__ scores,
                                               float* __restrict__ boxes) {
    __shared__ __align__(16) float sm[10240];   // Ax uses [0,8192); exchange uses [0,10240)
    __shared__ __align__(16) float Whs[2560];
    const int tid = threadIdx.x;
    const int p0  = blockIdx.x * 256;
    const int b   = blockIdx.y;
    const int pl  = tid & 63;     // 64 point-lanes, each 4 consecutive points
    const int og  = tid >> 6;     // 4 output groups of 18

    float acc[4][18] = {};

    for (int cc = 0; cc < 512; cc += 32) {
        __syncthreads();
        #pragma unroll
        for (int i = 0; i < 32; ++i) {
            int e = tid + i * 256;
            sm[e] = x[((size_t)(b * COUT + cc + (e >> 8)) << 13) + p0 + (e & 255)];
        }
        #pragma unroll
        for (int i = 0; i < 10; ++i) {
            int e = tid + i * 256;
            Whs[e] = Wht[cc * 80 + e];
        }
        __syncthreads();
        for (int kk = 0; kk < 32; ++kk) {
            float4 a4 = *(const float4*)&sm[kk * 256 + pl * 4];
            const float* wp = &Whs[kk * 80 + og * 20];
            #pragma unroll
            for (int k = 0; k < 18; ++k) {
                float wk = wp[k];
                acc[0][k] += a4.x * wk;
                acc[1][k] += a4.y * wk;
                acc[2][k] += a4.z * wk;
                acc[3][k] += a4.w * wk;
            }
        }
    }

    // epilogue in two halves of 128 points (LDS exchange)
    #pragma unroll 1
    for (int half = 0; half < 2; ++half) {
        __syncthreads();
        if ((pl >> 5) == half) {
            int plh = pl & 31;
            #pragma unroll
            for (int pi = 0; pi < 4; ++pi)
                #pragma unroll
                for (int k = 0; k < 18; ++k)
                    sm[(plh * 4 + pi) * 80 + og * 20 + k] = acc[pi][k];
        }
        __syncthreads();
        if (tid < 128) {
            const int pp = half * 128 + tid;
            const int p  = p0 + pp;
            float v[72];
            #pragma unroll
            for (int og2 = 0; og2 < 4; ++og2)
                #pragma unroll
                for (int k = 0; k < 18; ++k)
                    v[og2 * 18 + k] = sm[tid * 80 + og2 * 20 + k];

            const float im0 = iminfo[b * 3 + 0], im1 = iminfo[b * 3 + 1], im2 = iminfo[b * 3 + 2];
            const float hix = im2 - 1.f, hiy = im1 - 1.f, hiz = im0 - 1.f;
            const int d = p >> 10, h = (p >> 5) & 31, w = p & 31;
            const float sx = w * 8.f, sy = h * 8.f, sz = d * 8.f;

            #pragma unroll 1
            for (int a = 0; a < 9; ++a) {
                float c0 = v[a] + bcls[a];
                float c1 = v[9 + a] + bcls[9 + a];
                float m  = fmaxf(c0, c1);
                float e0 = expf(c0 - m), e1 = expf(c1 - m);
                scores[b * NANCH + p * 9 + a] = e1 / (e0 + e1);

                // base anchor sizes (exact powers of two scaling)
                float aw = (float)(32 << (a % 3));                 // x,y size = 8*SCALES
                float ad = aw * 0.5f * (float)(1 << (a / 3));      // z size = aw*RATIOS
                float ax1 = sx + 3.5f - 0.5f * (aw - 1.f);
                float ax2 = sx + 3.5f + 0.5f * (aw - 1.f);
                float ay1 = sy + 3.5f - 0.5f * (aw - 1.f);
                float ay2 = sy + 3.5f + 0.5f * (aw - 1.f);
                float az1 = sz + 3.5f - 0.5f * (ad - 1.f);
                float az2 = sz + 3.5f + 0.5f * (ad - 1.f);
                float ww_ = ax2 - ax1 + 1.f, hh_ = ay2 - ay1 + 1.f, dd_ = az2 - az1 + 1.f;
                float cx = ax1 + 0.5f * ww_, cy = ay1 + 0.5f * hh_, cz = az1 + 0.5f * dd_;

                const float* dv = &v[18 + a * 6];
                float dx = dv[0] + bbb[a * 6 + 0];
                float dy = dv[1] + bbb[a * 6 + 1];
                float dz = dv[2] + bbb[a * 6 + 2];
                float dw = dv[3] + bbb[a * 6 + 3];
                float dh = dv[4] + bbb[a * 6 + 4];
                float dd2 = dv[5] + bbb[a * 6 + 5];
                float pcx = dx * ww_ + cx, pcy = dy * hh_ + cy, pcz = dz * dd_ + cz;
                float pw = expf(dw) * ww_, ph = expf(dh) * hh_, pd = expf(dd2) * dd_;
                float x1 = fminf(fmaxf(pcx - 0.5f * pw, 0.f), hix);
                float y1 = fminf(fmaxf(pcy - 0.5f * ph, 0.f), hiy);
                float z1 = fminf(fmaxf(pcz - 0.5f * pd, 0.f), hiz);
                float x2 = fminf(fmaxf(pcx + 0.5f * pw, 0.f), hix);
                float y2 = fminf(fmaxf(pcy + 0.5f * ph, 0.f), hiy);
                float z2 = fminf(fmaxf(pcz + 0.5f * pd, 0.f), hiz);
                float* bp = &boxes[(size_t)(b * NANCH + p * 9 + a) * 6];
                bp[0] = x1; bp[1] = y1; bp[2] = z1; bp[3] = x2; bp[4] = y2; bp[5] = z2;
            }
        }
    }
}

// ---------------- exact rank-2048 radix select on key64 = (~u)<<32 | idx ----------------
__global__ __launch_bounds__(1024) void k_select(const float* __restrict__ scores,
                                                 unsigned long long* __restrict__ kbound) {
    __shared__ unsigned int hist[256];
    __shared__ unsigned long long sh_kept;
    __shared__ unsigned int sh_r;
    const int b = blockIdx.x, tid = threadIdx.x;
    const float* sc = scores + b * NANCH;
    if (tid == 0) { sh_kept = 0ull; sh_r = PRE; }
    __syncthreads();
    for (int bp = 7; bp >= 0; --bp) {
        if (tid < 256) hist[tid] = 0;
        __syncthreads();
        unsigned long long kept = sh_kept;
        unsigned int r = sh_r;
        for (int i = tid; i < NANCH; i += 1024) {
            unsigned int u = __float_as_uint(sc[i]);
            unsigned long long key = ((unsigned long long)(~u) << 32) | (unsigned)i;
            bool ok = (bp == 7) || ((key >> ((bp + 1) * 8)) == kept);
            if (ok) atomicAdd(&hist[(unsigned)((key >> (bp * 8)) & 255ull)], 1u);
        }
        __syncthreads();
        if (tid == 0) {
            unsigned int cum = 0; int chosen = 255;
            for (int bin = 0; bin < 256; ++bin) {
                unsigned int c = hist[bin];
                if (cum + c >= r) { chosen = bin; sh_r = r - cum; break; }
                cum += c;
            }
            sh_kept = (kept << 8) | (unsigned long long)chosen;
        }
        __syncthreads();
    }
    if (tid == 0) kbound[b] = sh_kept;
}

__global__ void k_compact(const float* __restrict__ scores,
                          const unsigned long long* __restrict__ kbound,
                          unsigned int* __restrict__ cnt,
                          unsigned long long* __restrict__ selkey) {
    int g = blockIdx.x * blockDim.x + threadIdx.x;
    if (g >= BATCH * NANCH) return;
    int b = g / NANCH, i = g % NANCH;
    unsigned int u = __float_as_uint(scores[g]);
    unsigned long long key = ((unsigned long long)(~u) << 32) | (unsigned)i;
    if (key <= kbound[b]) {
        unsigned int pos = atomicAdd(&cnt[b], 1u);
        selkey[b * PRE + pos] = key;
    }
}

// bitonic sort 2048 keys + gather sorted boxes
__global__ __launch_bounds__(1024) void k_sort(const unsigned long long* __restrict__ selkey,
                                               const float* __restrict__ boxes,
                                               float* __restrict__ sboxes) {
    __shared__ unsigned long long sk[PRE];
    const int b = blockIdx.x, tid = threadIdx.x;
    sk[tid] = selkey[b * PRE + tid];
    sk[tid + 1024] = selkey[b * PRE + tid + 1024];
    __syncthreads();
    for (int k = 2; k <= PRE; k <<= 1) {
        for (int j = k >> 1; j > 0; j >>= 1) {
            #pragma unroll 1
            for (int i = tid; i < PRE; i += 1024) {
                int ixj = i ^ j;
                if (ixj > i) {
                    unsigned long long va = sk[i], vb = sk[ixj];
                    bool up = ((i & k) == 0);
                    if ((va > vb) == up) { sk[i] = vb; sk[ixj] = va; }
                }
            }
            __syncthreads();
        }
    }
    for (int r = tid; r < PRE; r += 1024) {
        unsigned int n = (unsigned int)(sk[r] & 0xFFFFFFFFull);
        const float* src = &boxes[(size_t)(b * NANCH + (int)n) * 6];
        float* dst = &sboxes[(size_t)(b * PRE + r) * 6];
        #pragma unroll
        for (int c = 0; c < 6; ++c) dst[c] = src[c];
    }
}

// suppression bitmask: mask[b][i][w] bit j  <=>  j>i && IoU(i,j)>0.7
__global__ __launch_bounds__(256) void k_mask(const float* __restrict__ sboxes,
                                              unsigned long long* __restrict__ mask) {
    __shared__ float rb[64 * 6], cb[64 * 6];
    const int i0 = blockIdx.x * 64, j0 = blockIdx.y * 64, b = blockIdx.z;
    const int tid = threadIdx.x;
    for (int e = tid; e < 384; e += 256) {
        rb[e] = sboxes[(size_t)(b * PRE + i0) * 6 + e];
        cb[e] = sboxes[(size_t)(b * PRE + j0) * 6 + e];
    }
    __syncthreads();
    const int wave = tid >> 6, lane = tid & 63;
    const float bx1 = cb[lane * 6 + 0], by1 = cb[lane * 6 + 1], bz1 = cb[lane * 6 + 2];
    const float bx2 = cb[lane * 6 + 3], by2 = cb[lane * 6 + 4], bz2 = cb[lane * 6 + 5];
    const float vb = (bx2 - bx1 + 1.f) * (by2 - by1 + 1.f) * (bz2 - bz1 + 1.f);
    const int j = j0 + lane;
    for (int rr = 0; rr < 16; ++rr) {
        const int il = wave * 16 + rr;
        const int i = i0 + il;
        float ax1 = rb[il * 6 + 0], ay1 = rb[il * 6 + 1], az1 = rb[il * 6 + 2];
        float ax2 = rb[il * 6 + 3], ay2 = rb[il * 6 + 4], az2 = rb[il * 6 + 5];
        float va = (ax2 - ax1 + 1.f) * (ay2 - ay1 + 1.f) * (az2 - az1 + 1.f);
        float ix = fmaxf(fminf(ax2, bx2) - fmaxf(ax1, bx1) + 1.f, 0.f);
        float iy = fmaxf(fminf(ay2, by2) - fmaxf(ay1, by1) + 1.f, 0.f);
        float iz = fmaxf(fminf(az2, bz2) - fmaxf(az1, bz1) + 1.f, 0.f);
        float inter = ix * iy * iz;
        float iou = inter / (va + vb - inter);
        bool bit = (j > i) && (iou > NMS_TH);
        unsigned long long word = __ballot(bit);
        if (lane == 0) mask[(size_t)(b * PRE + i) * 32 + (j0 >> 6)] = word;
    }
}

// single-wave greedy NMS scan + ROI output
__global__ __launch_bounds__(64) void k_nms(const unsigned long long* __restrict__ mask,
                                            const float* __restrict__ sboxes,
                                            float* __restrict__ out) {
    const int b = blockIdx.x, lane = threadIdx.x;
    __shared__ int sel[POST];
    unsigned long long keep = ~0ull;          // lane l<32 owns bits [64l,64l+64)
    const unsigned long long* mrow = mask + (size_t)b * PRE * 32;
    const int lw = lane & 31;
    unsigned long long nxt = mrow[lw];
    int kcount = 0;
    for (int i = 0; i < PRE; ++i) {
        unsigned long long cur = nxt;
        if (i + 1 < PRE) nxt = mrow[(size_t)(i + 1) * 32 + lw];
        unsigned long long kw = __shfl(keep, i >> 6);
        if ((kw >> (i & 63)) & 1ull) {
            if (lane < 32) keep &= ~cur;
            if (kcount < POST && lane == 0) sel[kcount] = i;
            ++kcount;
            if (kcount >= POST) break;
        }
    }
    __syncthreads();
    const int kc = kcount;
    for (int r = lane; r < POST; r += 64) {
        float* op = &out[(size_t)(b * POST + r) * 7];
        op[0] = (float)b;
        if (r < kc) {
            const float* sb = &sboxes[(size_t)(b * PRE + sel[r]) * 6];
            #pragma unroll
            for (int c = 0; c < 6; ++c) op[1 + c] = sb[c];
        } else {
            #pragma unroll
            for (int c = 0; c < 6; ++c) op[1 + c] = 0.f;
        }
    }
}

extern "C" void kernel_launch(void* const* d_in, const int* in_sizes, int n_in,
                              void* d_out, int out_size, void* d_ws, size_t ws_size,
                              hipStream_t stream) {
    const float* base_feat = (const float*)d_in[0];
    const float* im_info   = (const float*)d_in[1];
    const float* W_conv    = (const float*)d_in[4];
    const float* b_conv    = (const float*)d_in[5];
    const float* W_cls     = (const float*)d_in[6];
    const float* b_cls     = (const float*)d_in[7];
    const float* W_bbox    = (const float*)d_in[8];
    const float* b_bbox    = (const float*)d_in[9];

    char* ws = (char*)d_ws;
    float* Wt      = (float*)(ws + OFF_WT);
    float* Wht     = (float*)(ws + OFF_WHT);
    float* x       = (float*)(ws + OFF_X);
    float* scores  = (float*)(ws + OFF_SC);
    float* boxes   = (float*)(ws + OFF_BX);
    unsigned long long* selkey = (unsigned long long*)(ws + OFF_SK);
    float* sboxes  = (float*)(ws + OFF_SB);
    unsigned long long* mask   = (unsigned long long*)(ws + OFF_MK);
    unsigned long long* kbound = (unsigned long long*)(ws + OFF_KB);
    unsigned int* cnt = (unsigned int*)(ws + OFF_CNT);

    hipMemsetAsync(cnt, 0, 16, stream);

    k_wtrans<<<(27 * 128 * 512 + 255) / 256, 256, 0, stream>>>(W_conv, Wt);
    k_whtrans<<<(512 * 80 + 255) / 256, 256, 0, stream>>>(W_cls, W_bbox, Wht);
    k_conv<<<dim3(128, 8, 2), 256, 0, stream>>>(base_feat, Wt, b_conv, x);
    k_heads<<<dim3(32, 2), 256, 0, stream>>>(x, Wht, b_cls, b_bbox, im_info, scores, boxes);
    k_select<<<2, 1024, 0, stream>>>(scores, kbound);
    k_compact<<<(BATCH * NANCH + 255) / 256, 256, 0, stream>>>(scores, kbound, cnt, selkey);
    k_sort<<<2, 1024, 0, stream>>>(selkey, boxes, sboxes);
    k_mask<<<dim3(32, 32, 2), 256, 0, stream>>>(sboxes, mask);
    k_nms<<<2, 64, 0, stream>>>(mask, sboxes, (float*)d_out);
}

// Round 2
// 1267.823 us; speedup vs baseline: 1.2873x; 1.2873x over previous
//
#include <hip/hip_runtime.h>
#include <hip/hip_bf16.h>
#include <stdint.h>

// Problem constants
#define BATCH 2
#define CIN 128
#define COUT 512
#define DD 8
#define HH 32
#define WW2 32
#define PSPAT 8192          // D*H*W
#define NA 9                // anchors per position
#define NANCH 73728         // PSPAT*NA
#define PRE 2048
#define POST 300
#define NMS_TH 0.7f

// ws layout (byte offsets, all 16B aligned)
constexpr size_t OFF_WT  = 0;          // 27*128*512 f32   = 7,077,888 B
constexpr size_t OFF_WHT = 7077888;    // 512*80 f32       = 163,840 B
constexpr size_t OFF_X   = 7241728;    // 2*512*8192 f32   = 33,554,432 B
constexpr size_t OFF_SC  = 40796160;   // 2*73728 f32      = 589,824 B
constexpr size_t OFF_BX  = 41385984;   // 2*73728*6 f32    = 3,538,944 B
constexpr size_t OFF_SK  = 44924928;   // 2*2048 u64       = 32,768 B
constexpr size_t OFF_SB  = 44957696;   // 2*2048*6 f32     = 98,304 B
constexpr size_t OFF_MK  = 45056000;   // 2*2048*32 u64    = 1,048,576 B
constexpr size_t OFF_KB  = 46104576;   // 2 u64
constexpr size_t OFF_CNT = 46104592;   // 2 u32 (+pad)

// ---------------- weight transforms ----------------
__global__ void k_wtrans(const float* __restrict__ Wc, float* __restrict__ Wt) {
    int e = blockIdx.x * blockDim.x + threadIdx.x;
    if (e >= 27 * 128 * 512) return;
    int co  = e & 511;
    int ci  = (e >> 9) & 127;
    int tap = e >> 16;
    Wt[e] = Wc[(co * 128 + ci) * 27 + tap];
}

// Wht[c][q], q = og*20 + k (k<18 real), output o = og*18 + k
__global__ void k_whtrans(const float* __restrict__ Wcls, const float* __restrict__ Wbb,
                          float* __restrict__ Wht) {
    int e = blockIdx.x * blockDim.x + threadIdx.x;
    if (e >= 512 * 80) return;
    int q = e % 80;
    int c = e / 80;
    int og = q / 20, k = q % 20;
    int o = og * 18 + k;
    float v = 0.f;
    if (k < 18) v = (o < 18) ? Wcls[o * 512 + c] : Wbb[(o - 18) * 512 + c];
    Wht[e] = v;
}

// ---------------- conv3d 3x3x3 + bias + relu (implicit GEMM, fp32) ----------------
// Block tile: 128 spatial x 128 cout. 256 threads, each 8x8 register tile.
// LDS traffic: 16 floats per 64 FMA per thread (1 B/FMA) -> ~balanced vs SIMD FMA rate.
__global__ __launch_bounds__(256) void k_conv(const float* __restrict__ in,
                                              const float* __restrict__ Wt,
                                              const float* __restrict__ bconv,
                                              float* __restrict__ x) {
    __shared__ __align__(16) float As[32 * 128];   // 16 KB
    __shared__ __align__(16) float Bs[32 * 128];   // 16 KB
    const int tid  = threadIdx.x;
    const int p0   = blockIdx.x * 128;   // spatial tile: fixed d, 4 h-rows
    const int co0  = blockIdx.y * 128;
    const int b    = blockIdx.z;
    const int d0   = p0 >> 10;
    const int h0   = (p0 >> 5) & 31;
    const int tp4  = (tid & 15) * 4;     // spatial frag base
    const int tco4 = (tid >> 4) * 4;     // cout frag base

    float acc[8][8] = {};

    for (int tap = 0; tap < 27; ++tap) {
        const int kd = tap / 9, kh = (tap / 3) % 3, kw = tap % 3;
        const int id = d0 + kd - 1;
        if (id < 0 || id >= DD) continue;   // uniform over block
        for (int cc = 0; cc < CIN; cc += 32) {
            __syncthreads();
            // stage A: input tile [kk 0..31][sp 0..127], shifted by (kh-1, kw-1)
            #pragma unroll
            for (int i = 0; i < 16; ++i) {
                int e  = tid + i * 256;
                int kk = e >> 7, sp = e & 127;
                int h  = h0 + (sp >> 5) + kh - 1;
                int w  = (sp & 31) + kw - 1;
                float v = 0.f;
                if ((unsigned)h < 32u && (unsigned)w < 32u)
                    v = in[(((b * CIN + cc + kk) * DD + id) << 10) + (h << 5) + w];
                As[kk * 128 + sp] = v;
            }
            // stage B: weights [kk][col] as float4
            #pragma unroll
            for (int i = 0; i < 4; ++i) {
                int e4 = tid + i * 256;          // 1024 float4s
                int kk = e4 >> 5;
                int c4 = (e4 & 31) * 4;
                *(float4*)&Bs[kk * 128 + c4] =
                    *(const float4*)&Wt[(tap * 128 + cc + kk) * 512 + co0 + c4];
            }
            __syncthreads();
            #pragma unroll 8
            for (int kk = 0; kk < 32; ++kk) {
                float4 a0 = *(const float4*)&As[kk * 128 + tp4];
                float4 a1 = *(const float4*)&As[kk * 128 + tp4 + 64];
                float4 b0 = *(const float4*)&Bs[kk * 128 + tco4];
                float4 b1 = *(const float4*)&Bs[kk * 128 + tco4 + 64];
                float av[8] = {a0.x, a0.y, a0.z, a0.w, a1.x, a1.y, a1.z, a1.w};
                float bv[8] = {b0.x, b0.y, b0.z, b0.w, b1.x, b1.y, b1.z, b1.w};
                #pragma unroll
                for (int i = 0; i < 8; ++i)
                    #pragma unroll
                    for (int j = 0; j < 8; ++j)
                        acc[i][j] += bv[i] * av[j];
            }
        }
    }
    // epilogue: bias + relu, two float4 stores per cout row
    #pragma unroll
    for (int i = 0; i < 8; ++i) {
        int co = co0 + tco4 + (i & 3) + ((i >> 2) * 64);
        float bias = bconv[co];
        float4 r0, r1;
        r0.x = fmaxf(acc[i][0] + bias, 0.f);
        r0.y = fmaxf(acc[i][1] + bias, 0.f);
        r0.z = fmaxf(acc[i][2] + bias, 0.f);
        r0.w = fmaxf(acc[i][3] + bias, 0.f);
        r1.x = fmaxf(acc[i][4] + bias, 0.f);
        r1.y = fmaxf(acc[i][5] + bias, 0.f);
        r1.z = fmaxf(acc[i][6] + bias, 0.f);
        r1.w = fmaxf(acc[i][7] + bias, 0.f);
        float* xp = &x[((size_t)(b * COUT + co) << 13) + p0 + tp4];
        *(float4*)xp = r0;
        *(float4*)(xp + 64) = r1;
    }
}

// ---------------- heads GEMM + score/box epilogue ----------------
__global__ __launch_bounds__(256) void k_heads(const float* __restrict__ x,
                                               const float* __restrict__ Wht,
                                               const float* __restrict__ bcls,
                                               const float* __restrict__ bbb,
                                               const float* __restrict__ iminfo,
                                               float* __restrict__ scores,
                                               float* __restrict__ boxes) {
    __shared__ __align__(16) float sm[10240];   // Ax uses [0,8192); exchange uses [0,10240)
    __shared__ __align__(16) float Whs[2560];
    const int tid = threadIdx.x;
    const int p0  = blockIdx.x * 256;
    const int b   = blockIdx.y;
    const int pl  = tid & 63;     // 64 point-lanes, each 4 consecutive points
    const int og  = tid >> 6;     // 4 output groups of 18

    float acc[4][18] = {};

    for (int cc = 0; cc < 512; cc += 32) {
        __syncthreads();
        #pragma unroll
        for (int i = 0; i < 32; ++i) {
            int e = tid + i * 256;
            sm[e] = x[((size_t)(b * COUT + cc + (e >> 8)) << 13) + p0 + (e & 255)];
        }
        #pragma unroll
        for (int i = 0; i < 10; ++i) {
            int e = tid + i * 256;
            Whs[e] = Wht[cc * 80 + e];
        }
        __syncthreads();
        for (int kk = 0; kk < 32; ++kk) {
            float4 a4 = *(const float4*)&sm[kk * 256 + pl * 4];
            const float* wp = &Whs[kk * 80 + og * 20];
            #pragma unroll
            for (int k = 0; k < 18; ++k) {
                float wk = wp[k];
                acc[0][k] += a4.x * wk;
                acc[1][k] += a4.y * wk;
                acc[2][k] += a4.z * wk;
                acc[3][k] += a4.w * wk;
            }
        }
    }

    // epilogue in two halves of 128 points (LDS exchange)
    #pragma unroll 1
    for (int half = 0; half < 2; ++half) {
        __syncthreads();
        if ((pl >> 5) == half) {
            int plh = pl & 31;
            #pragma unroll
            for (int pi = 0; pi < 4; ++pi)
                #pragma unroll
                for (int k = 0; k < 18; ++k)
                    sm[(plh * 4 + pi) * 80 + og * 20 + k] = acc[pi][k];
        }
        __syncthreads();
        if (tid < 128) {
            const int pp = half * 128 + tid;
            const int p  = p0 + pp;
            float v[72];
            #pragma unroll
            for (int og2 = 0; og2 < 4; ++og2)
                #pragma unroll
                for (int k = 0; k < 18; ++k)
                    v[og2 * 18 + k] = sm[tid * 80 + og2 * 20 + k];

            const float im0 = iminfo[b * 3 + 0], im1 = iminfo[b * 3 + 1], im2 = iminfo[b * 3 + 2];
            const float hix = im2 - 1.f, hiy = im1 - 1.f, hiz = im0 - 1.f;
            const int d = p >> 10, h = (p >> 5) & 31, w = p & 31;
            const float sx = w * 8.f, sy = h * 8.f, sz = d * 8.f;

            #pragma unroll 1
            for (int a = 0; a < 9; ++a) {
                float c0 = v[a] + bcls[a];
                float c1 = v[9 + a] + bcls[9 + a];
                float m  = fmaxf(c0, c1);
                float e0 = expf(c0 - m), e1 = expf(c1 - m);
                scores[b * NANCH + p * 9 + a] = e1 / (e0 + e1);

                // base anchor sizes (exact powers of two scaling)
                float aw = (float)(32 << (a % 3));                 // x,y size = 8*SCALES
                float ad = aw * 0.5f * (float)(1 << (a / 3));      // z size = aw*RATIOS
                float ax1 = sx + 3.5f - 0.5f * (aw - 1.f);
                float ax2 = sx + 3.5f + 0.5f * (aw - 1.f);
                float ay1 = sy + 3.5f - 0.5f * (aw - 1.f);
                float ay2 = sy + 3.5f + 0.5f * (aw - 1.f);
                float az1 = sz + 3.5f - 0.5f * (ad - 1.f);
                float az2 = sz + 3.5f + 0.5f * (ad - 1.f);
                float ww_ = ax2 - ax1 + 1.f, hh_ = ay2 - ay1 + 1.f, dd_ = az2 - az1 + 1.f;
                float cx = ax1 + 0.5f * ww_, cy = ay1 + 0.5f * hh_, cz = az1 + 0.5f * dd_;

                const float* dv = &v[18 + a * 6];
                float dx = dv[0] + bbb[a * 6 + 0];
                float dy = dv[1] + bbb[a * 6 + 1];
                float dz = dv[2] + bbb[a * 6 + 2];
                float dw = dv[3] + bbb[a * 6 + 3];
                float dh = dv[4] + bbb[a * 6 + 4];
                float dd2 = dv[5] + bbb[a * 6 + 5];
                float pcx = dx * ww_ + cx, pcy = dy * hh_ + cy, pcz = dz * dd_ + cz;
                float pw = expf(dw) * ww_, ph = expf(dh) * hh_, pd = expf(dd2) * dd_;
                float x1 = fminf(fmaxf(pcx - 0.5f * pw, 0.f), hix);
                float y1 = fminf(fmaxf(pcy - 0.5f * ph, 0.f), hiy);
                float z1 = fminf(fmaxf(pcz - 0.5f * pd, 0.f), hiz);
                float x2 = fminf(fmaxf(pcx + 0.5f * pw, 0.f), hix);
                float y2 = fminf(fmaxf(pcy + 0.5f * ph, 0.f), hiy);
                float z2 = fminf(fmaxf(pcz + 0.5f * pd, 0.f), hiz);
                float* bp = &boxes[(size_t)(b * NANCH + p * 9 + a) * 6];
                bp[0] = x1; bp[1] = y1; bp[2] = z1; bp[3] = x2; bp[4] = y2; bp[5] = z2;
            }
        }
    }
}

// ---------------- exact rank-2048 radix select on key64 = (~u)<<32 | idx ----------------
__global__ __launch_bounds__(1024) void k_select(const float* __restrict__ scores,
                                                 unsigned long long* __restrict__ kbound) {
    __shared__ unsigned int hist[256];
    __shared__ unsigned long long sh_kept;
    __shared__ unsigned int sh_r;
    const int b = blockIdx.x, tid = threadIdx.x;
    const float* sc = scores + b * NANCH;
    if (tid == 0) { sh_kept = 0ull; sh_r = PRE; }
    __syncthreads();
    for (int bp = 7; bp >= 0; --bp) {
        if (tid < 256) hist[tid] = 0;
        __syncthreads();
        unsigned long long kept = sh_kept;
        unsigned int r = sh_r;
        for (int i = tid; i < NANCH; i += 1024) {
            unsigned int u = __float_as_uint(sc[i]);
            unsigned long long key = ((unsigned long long)(~u) << 32) | (unsigned)i;
            bool ok = (bp == 7) || ((key >> ((bp + 1) * 8)) == kept);
            if (ok) atomicAdd(&hist[(unsigned)((key >> (bp * 8)) & 255ull)], 1u);
        }
        __syncthreads();
        if (tid == 0) {
            unsigned int cum = 0; int chosen = 255;
            for (int bin = 0; bin < 256; ++bin) {
                unsigned int c = hist[bin];
                if (cum + c >= r) { chosen = bin; sh_r = r - cum; break; }
                cum += c;
            }
            sh_kept = (kept << 8) | (unsigned long long)chosen;
        }
        __syncthreads();
    }
    if (tid == 0) kbound[b] = sh_kept;
}

__global__ void k_compact(const float* __restrict__ scores,
                          const unsigned long long* __restrict__ kbound,
                          unsigned int* __restrict__ cnt,
                          unsigned long long* __restrict__ selkey) {
    int g = blockIdx.x * blockDim.x + threadIdx.x;
    if (g >= BATCH * NANCH) return;
    int b = g / NANCH, i = g % NANCH;
    unsigned int u = __float_as_uint(scores[g]);
    unsigned long long key = ((unsigned long long)(~u) << 32) | (unsigned)i;
    if (key <= kbound[b]) {
        unsigned int pos = atomicAdd(&cnt[b], 1u);
        selkey[b * PRE + pos] = key;
    }
}

// bitonic sort 2048 keys + gather sorted boxes
__global__ __launch_bounds__(1024) void k_sort(const unsigned long long* __restrict__ selkey,
                                               const float* __restrict__ boxes,
                                               float* __restrict__ sboxes) {
    __shared__ unsigned long long sk[PRE];
    const int b = blockIdx.x, tid = threadIdx.x;
    sk[tid] = selkey[b * PRE + tid];
    sk[tid + 1024] = selkey[b * PRE + tid + 1024];
    __syncthreads();
    for (int k = 2; k <= PRE; k <<= 1) {
        for (int j = k >> 1; j > 0; j >>= 1) {
            #pragma unroll 1
            for (int i = tid; i < PRE; i += 1024) {
                int ixj = i ^ j;
                if (ixj > i) {
                    unsigned long long va = sk[i], vb = sk[ixj];
                    bool up = ((i & k) == 0);
                    if ((va > vb) == up) { sk[i] = vb; sk[ixj] = va; }
                }
            }
            __syncthreads();
        }
    }
    for (int r = tid; r < PRE; r += 1024) {
        unsigned int n = (unsigned int)(sk[r] & 0xFFFFFFFFull);
        const float* src = &boxes[(size_t)(b * NANCH + (int)n) * 6];
        float* dst = &sboxes[(size_t)(b * PRE + r) * 6];
        #pragma unroll
        for (int c = 0; c < 6; ++c) dst[c] = src[c];
    }
}

// suppression bitmask: mask[b][i][w] bit j  <=>  j>i && IoU(i,j)>0.7
__global__ __launch_bounds__(256) void k_mask(const float* __restrict__ sboxes,
                                              unsigned long long* __restrict__ mask) {
    __shared__ float rb[64 * 6], cb[64 * 6];
    const int i0 = blockIdx.x * 64, j0 = blockIdx.y * 64, b = blockIdx.z;
    const int tid = threadIdx.x;
    for (int e = tid; e < 384; e += 256) {
        rb[e] = sboxes[(size_t)(b * PRE + i0) * 6 + e];
        cb[e] = sboxes[(size_t)(b * PRE + j0) * 6 + e];
    }
    __syncthreads();
    const int wave = tid >> 6, lane = tid & 63;
    const float bx1 = cb[lane * 6 + 0], by1 = cb[lane * 6 + 1], bz1 = cb[lane * 6 + 2];
    const float bx2 = cb[lane * 6 + 3], by2 = cb[lane * 6 + 4], bz2 = cb[lane * 6 + 5];
    const float vb = (bx2 - bx1 + 1.f) * (by2 - by1 + 1.f) * (bz2 - bz1 + 1.f);
    const int j = j0 + lane;
    for (int rr = 0; rr < 16; ++rr) {
        const int il = wave * 16 + rr;
        const int i = i0 + il;
        float ax1 = rb[il * 6 + 0], ay1 = rb[il * 6 + 1], az1 = rb[il * 6 + 2];
        float ax2 = rb[il * 6 + 3], ay2 = rb[il * 6 + 4], az2 = rb[il * 6 + 5];
        float va = (ax2 - ax1 + 1.f) * (ay2 - ay1 + 1.f) * (az2 - az1 + 1.f);
        float ix = fmaxf(fminf(ax2, bx2) - fmaxf(ax1, bx1) + 1.f, 0.f);
        float iy = fmaxf(fminf(ay2, by2) - fmaxf(ay1, by1) + 1.f, 0.f);
        float iz = fmaxf(fminf(az2, bz2) - fmaxf(az1, bz1) + 1.f, 0.f);
        float inter = ix * iy * iz;
        float iou = inter / (va + vb - inter);
        bool bit = (j > i) && (iou > NMS_TH);
        unsigned long long word = __ballot(bit);
        if (lane == 0) mask[(size_t)(b * PRE + i) * 32 + (j0 >> 6)] = word;
    }
}

// single-wave greedy NMS scan + ROI output
__global__ __launch_bounds__(64) void k_nms(const unsigned long long* __restrict__ mask,
                                            const float* __restrict__ sboxes,
                                            float* __restrict__ out) {
    const int b = blockIdx.x, lane = threadIdx.x;
    __shared__ int sel[POST];
    unsigned long long keep = ~0ull;          // lane l<32 owns bits [64l,64l+64)
    const unsigned long long* mrow = mask + (size_t)b * PRE * 32;
    const int lw = lane & 31;
    unsigned long long nxt = mrow[lw];
    int kcount = 0;
    for (int i = 0; i < PRE; ++i) {
        unsigned long long cur = nxt;
        if (i + 1 < PRE) nxt = mrow[(size_t)(i + 1) * 32 + lw];
        unsigned long long kw = __shfl(keep, i >> 6);
        if ((kw >> (i & 63)) & 1ull) {
            if (lane < 32) keep &= ~cur;
            if (kcount < POST && lane == 0) sel[kcount] = i;
            ++kcount;
            if (kcount >= POST) break;
        }
    }
    __syncthreads();
    const int kc = kcount;
    for (int r = lane; r < POST; r += 64) {
        float* op = &out[(size_t)(b * POST + r) * 7];
        op[0] = (float)b;
        if (r < kc) {
            const float* sb = &sboxes[(size_t)(b * PRE + sel[r]) * 6];
            #pragma unroll
            for (int c = 0; c < 6; ++c) op[1 + c] = sb[c];
        } else {
            #pragma unroll
            for (int c = 0; c < 6; ++c) op[1 + c] = 0.f;
        }
    }
}

extern "C" void kernel_launch(void* const* d_in, const int* in_sizes, int n_in,
                              void* d_out, int out_size, void* d_ws, size_t ws_size,
                              hipStream_t stream) {
    const float* base_feat = (const float*)d_in[0];
    const float* im_info   = (const float*)d_in[1];
    const float* W_conv    = (const float*)d_in[4];
    const float* b_conv    = (const float*)d_in[5];
    const float* W_cls     = (const float*)d_in[6];
    const float* b_cls     = (const float*)d_in[7];
    const float* W_bbox    = (const float*)d_in[8];
    const float* b_bbox    = (const float*)d_in[9];

    char* ws = (char*)d_ws;
    float* Wt      = (float*)(ws + OFF_WT);
    float* Wht     = (float*)(ws + OFF_WHT);
    float* x       = (float*)(ws + OFF_X);
    float* scores  = (float*)(ws + OFF_SC);
    float* boxes   = (float*)(ws + OFF_BX);
    unsigned long long* selkey = (unsigned long long*)(ws + OFF_SK);
    float* sboxes  = (float*)(ws + OFF_SB);
    unsigned long long* mask   = (unsigned long long*)(ws + OFF_MK);
    unsigned long long* kbound = (unsigned long long*)(ws + OFF_KB);
    unsigned int* cnt = (unsigned int*)(ws + OFF_CNT);

    hipMemsetAsync(cnt, 0, 16, stream);

    k_wtrans<<<(27 * 128 * 512 + 255) / 256, 256, 0, stream>>>(W_conv, Wt);
    k_whtrans<<<(512 * 80 + 255) / 256, 256, 0, stream>>>(W_cls, W_bbox, Wht);
    k_conv<<<dim3(64, 4, 2), 256, 0, stream>>>(base_feat, Wt, b_conv, x);
    k_heads<<<dim3(32, 2), 256, 0, stream>>>(x, Wht, b_cls, b_bbox, im_info, scores, boxes);
    k_select<<<2, 1024, 0, stream>>>(scores, kbound);
    k_compact<<<(BATCH * NANCH + 255) / 256, 256, 0, stream>>>(scores, kbound, cnt, selkey);
    k_sort<<<2, 1024, 0, stream>>>(selkey, boxes, sboxes);
    k_mask<<<dim3(32, 32, 2), 256, 0, stream>>>(sboxes, mask);
    k_nms<<<2, 64, 0, stream>>>(mask, sboxes, (float*)d_out);
}